// Round 15
// baseline (260.183 us; speedup 1.0000x reference)
//
#include <hip/hip_runtime.h>
#include <stdint.h>

typedef __attribute__((ext_vector_type(8))) short short8;   // 8 x bf16 (4 VGPRs)
typedef __attribute__((ext_vector_type(4))) float f32x4;
typedef __attribute__((ext_vector_type(4))) unsigned short u16x4;
typedef unsigned short bf16_t;

__device__ __forceinline__ bf16_t f2bf(float f) {
  union { float f; uint32_t u; } x; x.f = f;
  uint32_t r = x.u + 0x7fffu + ((x.u >> 16) & 1u);   // RNE
  return (bf16_t)(r >> 16);
}

// async global->LDS 16B (LDS dest = wave-uniform base + lane*16)
__device__ __forceinline__ void ld_g2l_16(const bf16_t* g, bf16_t* l) {
  __builtin_amdgcn_global_load_lds(
      (const __attribute__((address_space(1))) void*)g,
      (__attribute__((address_space(3))) void*)l, 16, 0, 0);
}

// ------ fused fp32 -> bf16 convert for all 7 tensors + RoPE tables ------------
// threads 0..131071 also write one CS/SN entry each (2048 pos x 64 freq).
__global__ void convert_all(const float* __restrict__ s0, const float* __restrict__ s1,
                            const float* __restrict__ s2, const float* __restrict__ s3,
                            const float* __restrict__ s4, const float* __restrict__ s5,
                            const float* __restrict__ s6,
                            bf16_t* __restrict__ d0, bf16_t* __restrict__ d1,
                            bf16_t* __restrict__ d2, bf16_t* __restrict__ d3,
                            bf16_t* __restrict__ d4, bf16_t* __restrict__ d5,
                            bf16_t* __restrict__ d6,
                            float* __restrict__ CS, float* __restrict__ SN) {
  int i = blockIdx.x * 256 + threadIdx.x;
  if (i < 131072) {
    int fi = i & 63, pos = i >> 6;
    float ang = (float)pos * exp2f((float)fi * -0.2076205059f);  // -log2(1e4)/64
    CS[i] = cosf(ang);
    SN[i] = sinf(ang);
  }
  const float* src; bf16_t* dst; int off;
  if (i < 5 * 1048576) {
    int t = i >> 20; off = i & 1048575;
    if (t == 0)      { src = s0; dst = d0; }
    else if (t == 1) { src = s1; dst = d1; }
    else if (t == 2) { src = s2; dst = d2; }
    else if (t == 3) { src = s3; dst = d3; }
    else             { src = s4; dst = d4; }
  } else {
    int j = i - 5 * 1048576;
    if (j < 262144) { src = s5; dst = d5; off = j; }
    else            { src = s6; dst = d6; off = j - 262144; }
  }
  f32x4 v = *(const f32x4*)(src + (size_t)off * 4);
  u16x4 o;
  o[0] = f2bf(v[0]); o[1] = f2bf(v[1]); o[2] = f2bf(v[2]); o[3] = f2bf(v[3]);
  *(u16x4*)(dst + (size_t)off * 4) = o;
}

// ---------------- NT GEMM core (R9-verified): 64x128 tile, BK=64 --------------
// 256 threads (4 waves as 2x2), wave tile 32x64, double-buffered, one barrier
// per 64-K step. XOR swizzle: global source col ^ (row&7), LINEAR
// global_load_lds dest, read addr ^ ((l16&7)<<3) -> conflict-free ds_read_b128.
// CLOSED (R10-13): 3-buf counted-vmcnt regressed (T4 needs deep phase-split);
// A-direct-from-global regressed (FETCH amplification + exposed latency).
// MODE 0: fp32 out[m*N+n]  MODE 2: bf16 out[n*2048+m] (V^T)
// MODE 3: RoPE(table) + scale*log2e, bf16 (Q)  MODE 4: RoPE(table), bf16 (K)
template <int MODE>
__device__ __forceinline__ void gemm_core(
    bf16_t* __restrict__ As, bf16_t* __restrict__ Bs,   // [2][64*64], [2][128*64]
    const bf16_t* __restrict__ A, const bf16_t* __restrict__ Bm,
    const float* __restrict__ bias, void* __restrict__ Cout,
    int N, int K, int m0, int n0,
    const float* __restrict__ CS, const float* __restrict__ SN) {
  const int tid = threadIdx.x;
  const int lane = tid & 63, quad = lane >> 4, l16 = lane & 15;
  const int wv = tid >> 6;
  const int wr = wv >> 1, wc = wv & 1;
  const int swz = (l16 & 7) << 3;            // read-side XOR (elem space)

  f32x4 acc[2][4];
  const f32x4 zf = {0.f, 0.f, 0.f, 0.f};
#pragma unroll
  for (int mi = 0; mi < 2; ++mi)
#pragma unroll
    for (int ni = 0; ni < 4; ++ni) acc[mi][ni] = zf;

  const int rT = tid >> 3;
  const int colsw = (((tid & 7) ^ (rT & 7)) << 3);
  const bf16_t* Ap0 = A + (size_t)(m0 + rT) * K + colsw;        // c = tid
  const bf16_t* Ap1 = A + (size_t)(m0 + rT + 32) * K + colsw;   // c = tid+256
  const bf16_t* Bp0 = Bm + (size_t)(n0 + rT) * K + colsw;       // c = tid
  const bf16_t* Bp1 = Bm + (size_t)(n0 + rT + 32) * K + colsw;  // c = tid+256
  const bf16_t* Bp2 = Bm + (size_t)(n0 + rT + 64) * K + colsw;  // c = tid+512
  const bf16_t* Bp3 = Bm + (size_t)(n0 + rT + 96) * K + colsw;  // c = tid+768

  auto STAGE = [&](int buf, int k0) {
    ld_g2l_16(Ap0 + k0, As + buf * 4096 + tid * 8);
    ld_g2l_16(Ap1 + k0, As + buf * 4096 + (tid + 256) * 8);
    ld_g2l_16(Bp0 + k0, Bs + buf * 8192 + tid * 8);
    ld_g2l_16(Bp1 + k0, Bs + buf * 8192 + (tid + 256) * 8);
    ld_g2l_16(Bp2 + k0, Bs + buf * 8192 + (tid + 512) * 8);
    ld_g2l_16(Bp3 + k0, Bs + buf * 8192 + (tid + 768) * 8);
  };

  STAGE(0, 0);
  __syncthreads();                 // barrier drains vmcnt: step 0 landed
  int buf = 0;

  for (int k0 = 0; k0 < K; k0 += 64) {
    if (k0 + 64 < K) STAGE(buf ^ 1, k0 + 64);   // prefetch overlaps compute
    const bf16_t* Ab = As + buf * 4096;
    const bf16_t* Bb = Bs + buf * 8192;
    short8 af[2][2], bfv[4][2];
#pragma unroll
    for (int mi = 0; mi < 2; ++mi) {
      int rowL = wr * 32 + mi * 16 + l16;
#pragma unroll
      for (int kc = 0; kc < 2; ++kc)
        af[mi][kc] = *(const short8*)(
            &Ab[rowL * 64 + ((kc * 32 + quad * 8) ^ swz)]);
    }
#pragma unroll
    for (int ni = 0; ni < 4; ++ni) {
      int rowB = wc * 32 + (ni & 1) * 16 + (ni >> 1) * 64 + l16;
#pragma unroll
      for (int kc = 0; kc < 2; ++kc)
        bfv[ni][kc] = *(const short8*)(
            &Bb[rowB * 64 + ((kc * 32 + quad * 8) ^ swz)]);
    }
#pragma unroll
    for (int kc = 0; kc < 2; ++kc)
#pragma unroll
      for (int mi = 0; mi < 2; ++mi)
#pragma unroll
        for (int ni = 0; ni < 4; ++ni)
          acc[mi][ni] = __builtin_amdgcn_mfma_f32_16x16x32_bf16(
              af[mi][kc], bfv[ni][kc], acc[mi][ni], 0, 0, 0);
    __asm__ volatile("s_waitcnt vmcnt(0)" ::: "memory");  // next step landed
    __syncthreads();   // one barrier/step: readers done + prefetch visible
    buf ^= 1;
  }

  // C/D layout: col = lane&15 (n), row = quad*4 + reg (m)
  if (MODE == 0 || MODE == 2) {
#pragma unroll
    for (int mi = 0; mi < 2; ++mi)
#pragma unroll
      for (int ni = 0; ni < 4; ++ni) {
        int n = n0 + wc * 32 + (ni & 1) * 16 + (ni >> 1) * 64 + l16;
        int mbase = m0 + wr * 32 + mi * 16 + quad * 4;
        float bv = bias[n];
#pragma unroll
        for (int r = 0; r < 4; ++r) {
          float v = acc[mi][ni][r] + bv;
          int m = mbase + r;
          if (MODE == 0) ((float*)Cout)[(size_t)m * N + n] = v;
          else           ((bf16_t*)Cout)[(size_t)n * 2048 + m] = f2bf(v);
        }
      }
  } else {
    // RoPE: i = wc*32 + ni*16 + l16 (ni<2), partner at ni+2 (i+64). pos = m.
    const float scale = (MODE == 3) ? 0.12751744f : 1.0f;   // rsqrt(128)*log2e
    bf16_t* dst = (bf16_t*)Cout;
#pragma unroll
    for (int mi = 0; mi < 2; ++mi)
#pragma unroll
      for (int r = 0; r < 4; ++r) {
        int m = m0 + wr * 32 + mi * 16 + quad * 4 + r;
#pragma unroll
        for (int ni = 0; ni < 2; ++ni) {
          int i = wc * 32 + ni * 16 + l16;
          int n_lo = n0 + i;
          float v1 = acc[mi][ni][r] + bias[n_lo];
          float v2 = acc[mi][ni + 2][r] + bias[n_lo + 64];
          float c = CS[m * 64 + i];
          float s = SN[m * 64 + i];
          float o1 = (v1 * c - v2 * s) * scale;
          float o2 = (v2 * c + v1 * s) * scale;
          dst[(size_t)m * N + n_lo] = f2bf(o1);
          dst[(size_t)m * N + n_lo + 64] = f2bf(o2);
        }
      }
  }
}

// fused Q/K/V projections. 768 blocks, XCD-aware job map.
__global__ __launch_bounds__(256) void gemm_qkv(
    const bf16_t* __restrict__ qb, const bf16_t* __restrict__ kb,
    const bf16_t* __restrict__ vb, const bf16_t* __restrict__ wqb,
    const bf16_t* __restrict__ wkb, const bf16_t* __restrict__ wvb,
    const float* __restrict__ bq, const float* __restrict__ bk,
    const float* __restrict__ bv, bf16_t* __restrict__ Qr,
    bf16_t* __restrict__ Kr, bf16_t* __restrict__ Vt,
    const float* __restrict__ CS, const float* __restrict__ SN) {
  __shared__ __align__(16) bf16_t As[2 * 64 * 64];
  __shared__ __align__(16) bf16_t Bs[2 * 128 * 64];
  int bid = blockIdx.x;
  int job = (bid & 7) * 96 + (bid >> 3);     // XCD-contiguous B tiles
  int bx = job >> 5, m0 = (job & 31) * 64;
  if (bx < 16)
    gemm_core<3>(As, Bs, qb, wqb, bq, Qr, 2048, 2048, m0, bx * 128, CS, SN);
  else if (bx < 20)
    gemm_core<4>(As, Bs, kb, wkb, bk, Kr, 512, 2048, m0, (bx - 16) * 128, CS, SN);
  else
    gemm_core<2>(As, Bs, vb, wvb, bv, Vt, 512, 2048, m0, (bx - 20) * 128, CS, SN);
}

// O projection. 512 blocks, XCD-aware job map.
__global__ __launch_bounds__(256) void gemm_o(
    const bf16_t* __restrict__ Ob, const bf16_t* __restrict__ wob,
    const float* __restrict__ bo, float* __restrict__ out) {
  __shared__ __align__(16) bf16_t As[2 * 64 * 64];
  __shared__ __align__(16) bf16_t Bs[2 * 128 * 64];
  int bid = blockIdx.x;
  int job = (bid & 7) * 64 + (bid >> 3);
  int bx = job >> 5, m0 = (job & 31) * 64;
  gemm_core<0>(As, Bs, Ob, wob, bo, out, 2048, 2048, m0, bx * 128,
               nullptr, nullptr);
}

// ---------------- causal GQA flash attention (R5-verified + T5 setprio) -------
// Structure CLOSED (6 variants regressed). NEW (R15): s_setprio(1) around the
// QK and PV MFMA clusters (T5). Applicability per m191: pays when the CU hosts
// independent blocks at DIFFERENT phases -- our complementary pairing (31+2
// trip counts) gives exactly that; the MFMA-entering wave preempts the other
// block's staging/VALU. (GEMM keeps no setprio: m190 showed it hurts
// barrier-locked lockstep blocks.)
__global__ __launch_bounds__(256, 2) void attn_fwd(
    const bf16_t* __restrict__ Qr, const bf16_t* __restrict__ Kr,
    const bf16_t* __restrict__ Vt, bf16_t* __restrict__ Oo) {
  const int h = blockIdx.y;
  const int bx = blockIdx.x;
  const int qt = (h < 8) ? (31 - bx) : bx;   // complementary co-resident pairing
  const int T = qt + 1;

  const int tid = threadIdx.x;
  const int wv = tid >> 6, lane = tid & 63, quad = lane >> 4, l16 = lane & 15;
  const int q_base = qt * 64 + wv * 16;
  const int hkv = h >> 2;
  const int qg = q_base + l16;               // this lane's q-row (B-operand col)
  const int swzE = (l16 & 7) << 3;           // element-space XOR swizzle (read)

  __shared__ __align__(16) bf16_t Ks[2][64 * 128];   // linear, swizzled content
  __shared__ __align__(16) bf16_t Vs[2][128 * 64];

  short8 qf[4];
  {
    const bf16_t* qp = Qr + (size_t)qg * 2048 + h * 128 + quad * 8;
#pragma unroll
    for (int kc = 0; kc < 4; ++kc) qf[kc] = *(const short8*)(qp + kc * 32);
  }

  const f32x4 zf = {0.f, 0.f, 0.f, 0.f};
  f32x4 o[8];
#pragma unroll
  for (int di = 0; di < 8; ++di) o[di] = zf;
  float l_acc = 0.f;

  auto STAGE = [&](int buf, int t) {
    const int k0 = t * 64;
    bf16_t* KB = &Ks[buf][0];
    bf16_t* VB = &Vs[buf][0];
#pragma unroll
    for (int m = 0; m < 4; ++m) {
      int rK = wv * 16 + m * 4 + (lane >> 4);          // K tile row (k-pos)
      const bf16_t* gK = Kr + (size_t)(k0 + rK) * 512 + hkv * 128
                         + (((lane & 15) ^ ((4 * (m & 1)) | quad)) << 3);
      ld_g2l_16(gK, KB + rK * 128 + ((lane & 15) << 3));
      int rV = wv * 32 + m * 8 + (lane >> 3);          // V tile row (d)
      const bf16_t* gV = Vt + (size_t)(hkv * 128 + rV) * 2048 + k0
                         + (((lane & 7) ^ ((lane >> 3) & 7)) << 3);
      ld_g2l_16(gV, VB + rV * 64 + ((lane & 7) << 3));
    }
  };

  STAGE(0, 0);
  __syncthreads();                // barrier drains vmcnt(0): tile 0 landed
  int buf = 0;

  for (int t = 0; t < T; ++t) {
    if (t + 1 < T) STAGE(buf ^ 1, t + 1);   // prefetch overlaps compute
    const bf16_t* KB = &Ks[buf][0];
    const bf16_t* VB = &Vs[buf][0];
    const int k0 = t * 64;

    // ---- swapped QK^T: sacc[sub][r] = S[k = sub*16+quad*4+r][q = l16] ----
    f32x4 sacc[4];
#pragma unroll
    for (int sub = 0; sub < 4; ++sub) sacc[sub] = zf;
    __builtin_amdgcn_s_setprio(1);           // T5: favor MFMA-entering wave
#pragma unroll
    for (int sub = 0; sub < 4; ++sub)
#pragma unroll
      for (int kc = 0; kc < 4; ++kc) {
        short8 kf = *(const short8*)(
            &KB[(sub * 16 + l16) * 128 + ((kc * 32 + quad * 8) ^ swzE)]);
        sacc[sub] = __builtin_amdgcn_mfma_f32_16x16x32_bf16(kf, qf[kc], sacc[sub], 0, 0, 0);
      }
    __builtin_amdgcn_s_setprio(0);

    // ---- lane-local softmax (fixed max, exp2) + pack to bf16 pairs ----
    const bool dg = (k0 + 63 > q_base);
    uint32_t Dw[4][2];
#pragma unroll
    for (int sub = 0; sub < 4; ++sub) {
      float pv[4];
#pragma unroll
      for (int r = 0; r < 4; ++r) {
        float e = exp2f(sacc[sub][r]);
        if (dg) {
          int kg = k0 + sub * 16 + quad * 4 + r;
          if (kg > qg) e = 0.f;
        }
        pv[r] = e;
        l_acc += e;
      }
      asm("v_cvt_pk_bf16_f32 %0, %1, %2" : "=v"(Dw[sub][0]) : "v"(pv[0]), "v"(pv[1]));
      asm("v_cvt_pk_bf16_f32 %0, %1, %2" : "=v"(Dw[sub][1]) : "v"(pv[2]), "v"(pv[3]));
    }

    // ---- C-layout -> A-fragment via ds_bpermute (reg crossbar) ----
    const int aA = ((((quad * 2) & 3) << 4) + l16) << 2;       // d = 0,1
    const int aB = ((((quad * 2 + 1) & 3) << 4) + l16) << 2;   // d = 2,3
    const bool losel = quad < 2;
#define BPERM(a, x) ((uint32_t)__builtin_amdgcn_ds_bpermute((a), (int)(x)))
    union { uint32_t w[4]; short8 v; } U0, U1;
    {
      uint32_t t0, t1;
      t0 = BPERM(aA, Dw[0][0]); t1 = BPERM(aA, Dw[1][0]); U0.w[0] = losel ? t0 : t1;
      t0 = BPERM(aA, Dw[0][1]); t1 = BPERM(aA, Dw[1][1]); U0.w[1] = losel ? t0 : t1;
      t0 = BPERM(aB, Dw[0][0]); t1 = BPERM(aB, Dw[1][0]); U0.w[2] = losel ? t0 : t1;
      t0 = BPERM(aB, Dw[0][1]); t1 = BPERM(aB, Dw[1][1]); U0.w[3] = losel ? t0 : t1;
      t0 = BPERM(aA, Dw[2][0]); t1 = BPERM(aA, Dw[3][0]); U1.w[0] = losel ? t0 : t1;
      t0 = BPERM(aA, Dw[2][1]); t1 = BPERM(aA, Dw[3][1]); U1.w[1] = losel ? t0 : t1;
      t0 = BPERM(aB, Dw[2][0]); t1 = BPERM(aB, Dw[3][0]); U1.w[2] = losel ? t0 : t1;
      t0 = BPERM(aB, Dw[2][1]); t1 = BPERM(aB, Dw[3][1]); U1.w[3] = losel ? t0 : t1;
    }
#undef BPERM
    const short8 pf0 = U0.v, pf1 = U1.v;

    // ---- PV accumulate from V-LDS (swizzled reads) ----
    __builtin_amdgcn_s_setprio(1);           // T5
#pragma unroll
    for (int di = 0; di < 8; ++di) {
      short8 vf0 = *(const short8*)(
          &VB[(di * 16 + l16) * 64 + ((quad * 8) ^ swzE)]);
      short8 vf1 = *(const short8*)(
          &VB[(di * 16 + l16) * 64 + ((quad * 8 + 32) ^ swzE)]);
      o[di] = __builtin_amdgcn_mfma_f32_16x16x32_bf16(pf0, vf0, o[di], 0, 0, 0);
      o[di] = __builtin_amdgcn_mfma_f32_16x16x32_bf16(pf1, vf1, o[di], 0, 0, 0);
    }
    __builtin_amdgcn_s_setprio(0);

    __asm__ volatile("s_waitcnt vmcnt(0)" ::: "memory");  // next tile landed
    __syncthreads();   // one barrier/tile: readers done + prefetch visible
    buf ^= 1;
  }

  // epilogue: reduce l across quads, normalize, write bf16
  float lf = l_acc;
  lf += __shfl_xor(lf, 16);
  lf += __shfl_xor(lf, 32);
  float linv[4];
#pragma unroll
  for (int r = 0; r < 4; ++r) linv[r] = 1.0f / __shfl(lf, quad * 4 + r, 64);
#pragma unroll
  for (int di = 0; di < 8; ++di)
#pragma unroll
    for (int r = 0; r < 4; ++r) {
      size_t row = q_base + quad * 4 + r;
      size_t col = h * 128 + di * 16 + l16;
      Oo[row * 2048 + col] = f2bf(o[di][r] * linv[r]);
    }
}

// ---------------- launch ------------------------------------------------------
extern "C" void kernel_launch(void* const* d_in, const int* in_sizes, int n_in,
                              void* d_out, int out_size, void* d_ws, size_t ws_size,
                              hipStream_t stream) {
  (void)in_sizes; (void)n_in; (void)out_size; (void)ws_size;
  const float* query = (const float*)d_in[0];
  const float* key = (const float*)d_in[1];
  const float* value = (const float*)d_in[2];
  const float* Wq = (const float*)d_in[3];
  const float* bq = (const float*)d_in[4];
  const float* Wk = (const float*)d_in[5];
  const float* bk = (const float*)d_in[6];
  const float* Wv = (const float*)d_in[7];
  const float* bv = (const float*)d_in[8];
  const float* Wo = (const float*)d_in[9];
  const float* bo = (const float*)d_in[10];
  float* out = (float*)d_out;

  char* ws = (char*)d_ws;
  const size_t MB = 1024 * 1024;
  bf16_t* qb  = (bf16_t*)(ws + 0 * MB);    // 8 MB
  bf16_t* kb  = (bf16_t*)(ws + 8 * MB);    // 8 MB
  bf16_t* vb  = (bf16_t*)(ws + 16 * MB);   // 8 MB
  bf16_t* wqb = (bf16_t*)(ws + 24 * MB);   // 8 MB
  bf16_t* wkb = (bf16_t*)(ws + 32 * MB);   // 2 MB
  bf16_t* wvb = (bf16_t*)(ws + 34 * MB);   // 2 MB
  bf16_t* wob = (bf16_t*)(ws + 36 * MB);   // 8 MB
  bf16_t* Qr  = (bf16_t*)(ws + 44 * MB);   // 8 MB  roped+scaled Q (x log2e)
  bf16_t* Kr  = (bf16_t*)(ws + 52 * MB);   // 2 MB  roped K
  bf16_t* Vt  = (bf16_t*)(ws + 54 * MB);   // 2 MB  V^T (512 x 2048)
  bf16_t* Ob  = (bf16_t*)(ws + 56 * MB);   // 8 MB  attn out (bf16)
  float*  CS  = (float*)(ws + 64 * MB);    // 512 KB rope cos table
  float*  SN  = (float*)(ws + 64 * MB + 512 * 1024);  // 512 KB rope sin

  convert_all<<<22528, 256, 0, stream>>>(query, key, value, Wq, Wo, Wk, Wv,
                                         qb, kb, vb, wqb, wob, wkb, wvb, CS, SN);
  gemm_qkv<<<768, 256, 0, stream>>>(qb, kb, vb, wqb, wkb, wvb,
                                    bq, bk, bv, Qr, Kr, Vt, CS, SN);
  attn_fwd<<<dim3(32, 16), 256, 0, stream>>>(Qr, Kr, Vt, Ob);
  gemm_o<<<512, 256, 0, stream>>>(Ob, wob, bo, out);
}

// Round 16
// 257.281 us; speedup vs baseline: 1.0113x; 1.0113x over previous
//
#include <hip/hip_runtime.h>
#include <stdint.h>

typedef __attribute__((ext_vector_type(8))) short short8;   // 8 x bf16 (4 VGPRs)
typedef __attribute__((ext_vector_type(4))) float f32x4;
typedef __attribute__((ext_vector_type(4))) unsigned short u16x4;
typedef unsigned short bf16_t;

__device__ __forceinline__ bf16_t f2bf(float f) {
  union { float f; uint32_t u; } x; x.f = f;
  uint32_t r = x.u + 0x7fffu + ((x.u >> 16) & 1u);   // RNE
  return (bf16_t)(r >> 16);
}

// async global->LDS 16B (LDS dest = wave-uniform base + lane*16)
__device__ __forceinline__ void ld_g2l_16(const bf16_t* g, bf16_t* l) {
  __builtin_amdgcn_global_load_lds(
      (const __attribute__((address_space(1))) void*)g,
      (__attribute__((address_space(3))) void*)l, 16, 0, 0);
}

// ------ fused fp32 -> bf16 convert for all 7 tensors + RoPE tables ------------
// threads 0..131071 also write one CS/SN entry each (2048 pos x 64 freq).
__global__ void convert_all(const float* __restrict__ s0, const float* __restrict__ s1,
                            const float* __restrict__ s2, const float* __restrict__ s3,
                            const float* __restrict__ s4, const float* __restrict__ s5,
                            const float* __restrict__ s6,
                            bf16_t* __restrict__ d0, bf16_t* __restrict__ d1,
                            bf16_t* __restrict__ d2, bf16_t* __restrict__ d3,
                            bf16_t* __restrict__ d4, bf16_t* __restrict__ d5,
                            bf16_t* __restrict__ d6,
                            float* __restrict__ CS, float* __restrict__ SN) {
  int i = blockIdx.x * 256 + threadIdx.x;
  if (i < 131072) {
    int fi = i & 63, pos = i >> 6;
    float ang = (float)pos * exp2f((float)fi * -0.2076205059f);  // -log2(1e4)/64
    CS[i] = cosf(ang);
    SN[i] = sinf(ang);
  }
  const float* src; bf16_t* dst; int off;
  if (i < 5 * 1048576) {
    int t = i >> 20; off = i & 1048575;
    if (t == 0)      { src = s0; dst = d0; }
    else if (t == 1) { src = s1; dst = d1; }
    else if (t == 2) { src = s2; dst = d2; }
    else if (t == 3) { src = s3; dst = d3; }
    else             { src = s4; dst = d4; }
  } else {
    int j = i - 5 * 1048576;
    if (j < 262144) { src = s5; dst = d5; off = j; }
    else            { src = s6; dst = d6; off = j - 262144; }
  }
  f32x4 v = *(const f32x4*)(src + (size_t)off * 4);
  u16x4 o;
  o[0] = f2bf(v[0]); o[1] = f2bf(v[1]); o[2] = f2bf(v[2]); o[3] = f2bf(v[3]);
  *(u16x4*)(dst + (size_t)off * 4) = o;
}

// ---------------- NT GEMM core (R9-verified): 64x128 tile, BK=64 --------------
// 256 threads (4 waves as 2x2), wave tile 32x64, double-buffered, one barrier
// per 64-K step. XOR swizzle: global source col ^ (row&7), LINEAR
// global_load_lds dest, read addr ^ ((l16&7)<<3) -> conflict-free ds_read_b128.
// CLOSED (R10-15): 3-buf counted-vmcnt regressed (T4 needs deep phase-split);
// A-direct-from-global regressed (FETCH amplification + exposed latency);
// T5 setprio regressed (barrier-locked waves).
// MODE 0: fp32 out[m*N+n]  MODE 2: bf16 out[n*2048+m] (V^T)
// MODE 3: RoPE(table) + scale*log2e, bf16 (Q)  MODE 4: RoPE(table), bf16 (K)
template <int MODE>
__device__ __forceinline__ void gemm_core(
    bf16_t* __restrict__ As, bf16_t* __restrict__ Bs,   // [2][64*64], [2][128*64]
    const bf16_t* __restrict__ A, const bf16_t* __restrict__ Bm,
    const float* __restrict__ bias, void* __restrict__ Cout,
    int N, int K, int m0, int n0,
    const float* __restrict__ CS, const float* __restrict__ SN) {
  const int tid = threadIdx.x;
  const int lane = tid & 63, quad = lane >> 4, l16 = lane & 15;
  const int wv = tid >> 6;
  const int wr = wv >> 1, wc = wv & 1;
  const int swz = (l16 & 7) << 3;            // read-side XOR (elem space)

  f32x4 acc[2][4];
  const f32x4 zf = {0.f, 0.f, 0.f, 0.f};
#pragma unroll
  for (int mi = 0; mi < 2; ++mi)
#pragma unroll
    for (int ni = 0; ni < 4; ++ni) acc[mi][ni] = zf;

  const int rT = tid >> 3;
  const int colsw = (((tid & 7) ^ (rT & 7)) << 3);
  const bf16_t* Ap0 = A + (size_t)(m0 + rT) * K + colsw;        // c = tid
  const bf16_t* Ap1 = A + (size_t)(m0 + rT + 32) * K + colsw;   // c = tid+256
  const bf16_t* Bp0 = Bm + (size_t)(n0 + rT) * K + colsw;       // c = tid
  const bf16_t* Bp1 = Bm + (size_t)(n0 + rT + 32) * K + colsw;  // c = tid+256
  const bf16_t* Bp2 = Bm + (size_t)(n0 + rT + 64) * K + colsw;  // c = tid+512
  const bf16_t* Bp3 = Bm + (size_t)(n0 + rT + 96) * K + colsw;  // c = tid+768

  auto STAGE = [&](int buf, int k0) {
    ld_g2l_16(Ap0 + k0, As + buf * 4096 + tid * 8);
    ld_g2l_16(Ap1 + k0, As + buf * 4096 + (tid + 256) * 8);
    ld_g2l_16(Bp0 + k0, Bs + buf * 8192 + tid * 8);
    ld_g2l_16(Bp1 + k0, Bs + buf * 8192 + (tid + 256) * 8);
    ld_g2l_16(Bp2 + k0, Bs + buf * 8192 + (tid + 512) * 8);
    ld_g2l_16(Bp3 + k0, Bs + buf * 8192 + (tid + 768) * 8);
  };

  STAGE(0, 0);
  __syncthreads();                 // barrier drains vmcnt: step 0 landed
  int buf = 0;

  for (int k0 = 0; k0 < K; k0 += 64) {
    if (k0 + 64 < K) STAGE(buf ^ 1, k0 + 64);   // prefetch overlaps compute
    const bf16_t* Ab = As + buf * 4096;
    const bf16_t* Bb = Bs + buf * 8192;
    short8 af[2][2], bfv[4][2];
#pragma unroll
    for (int mi = 0; mi < 2; ++mi) {
      int rowL = wr * 32 + mi * 16 + l16;
#pragma unroll
      for (int kc = 0; kc < 2; ++kc)
        af[mi][kc] = *(const short8*)(
            &Ab[rowL * 64 + ((kc * 32 + quad * 8) ^ swz)]);
    }
#pragma unroll
    for (int ni = 0; ni < 4; ++ni) {
      int rowB = wc * 32 + (ni & 1) * 16 + (ni >> 1) * 64 + l16;
#pragma unroll
      for (int kc = 0; kc < 2; ++kc)
        bfv[ni][kc] = *(const short8*)(
            &Bb[rowB * 64 + ((kc * 32 + quad * 8) ^ swz)]);
    }
#pragma unroll
    for (int kc = 0; kc < 2; ++kc)
#pragma unroll
      for (int mi = 0; mi < 2; ++mi)
#pragma unroll
        for (int ni = 0; ni < 4; ++ni)
          acc[mi][ni] = __builtin_amdgcn_mfma_f32_16x16x32_bf16(
              af[mi][kc], bfv[ni][kc], acc[mi][ni], 0, 0, 0);
    __asm__ volatile("s_waitcnt vmcnt(0)" ::: "memory");  // next step landed
    __syncthreads();   // one barrier/step: readers done + prefetch visible
    buf ^= 1;
  }

  // C/D layout: col = lane&15 (n), row = quad*4 + reg (m)
  if (MODE == 0 || MODE == 2) {
#pragma unroll
    for (int mi = 0; mi < 2; ++mi)
#pragma unroll
      for (int ni = 0; ni < 4; ++ni) {
        int n = n0 + wc * 32 + (ni & 1) * 16 + (ni >> 1) * 64 + l16;
        int mbase = m0 + wr * 32 + mi * 16 + quad * 4;
        float bv = bias[n];
#pragma unroll
        for (int r = 0; r < 4; ++r) {
          float v = acc[mi][ni][r] + bv;
          int m = mbase + r;
          if (MODE == 0) ((float*)Cout)[(size_t)m * N + n] = v;
          else           ((bf16_t*)Cout)[(size_t)n * 2048 + m] = f2bf(v);
        }
      }
  } else {
    // RoPE: i = wc*32 + ni*16 + l16 (ni<2), partner at ni+2 (i+64). pos = m.
    const float scale = (MODE == 3) ? 0.12751744f : 1.0f;   // rsqrt(128)*log2e
    bf16_t* dst = (bf16_t*)Cout;
#pragma unroll
    for (int mi = 0; mi < 2; ++mi)
#pragma unroll
      for (int r = 0; r < 4; ++r) {
        int m = m0 + wr * 32 + mi * 16 + quad * 4 + r;
#pragma unroll
        for (int ni = 0; ni < 2; ++ni) {
          int i = wc * 32 + ni * 16 + l16;
          int n_lo = n0 + i;
          float v1 = acc[mi][ni][r] + bias[n_lo];
          float v2 = acc[mi][ni + 2][r] + bias[n_lo + 64];
          float c = CS[m * 64 + i];
          float s = SN[m * 64 + i];
          float o1 = (v1 * c - v2 * s) * scale;
          float o2 = (v2 * c + v1 * s) * scale;
          dst[(size_t)m * N + n_lo] = f2bf(o1);
          dst[(size_t)m * N + n_lo + 64] = f2bf(o2);
        }
      }
  }
}

// fused Q/K/V projections. 768 blocks, XCD-aware job map.
__global__ __launch_bounds__(256) void gemm_qkv(
    const bf16_t* __restrict__ qb, const bf16_t* __restrict__ kb,
    const bf16_t* __restrict__ vb, const bf16_t* __restrict__ wqb,
    const bf16_t* __restrict__ wkb, const bf16_t* __restrict__ wvb,
    const float* __restrict__ bq, const float* __restrict__ bk,
    const float* __restrict__ bv, bf16_t* __restrict__ Qr,
    bf16_t* __restrict__ Kr, bf16_t* __restrict__ Vt,
    const float* __restrict__ CS, const float* __restrict__ SN) {
  __shared__ __align__(16) bf16_t As[2 * 64 * 64];
  __shared__ __align__(16) bf16_t Bs[2 * 128 * 64];
  int bid = blockIdx.x;
  int job = (bid & 7) * 96 + (bid >> 3);     // XCD-contiguous B tiles
  int bx = job >> 5, m0 = (job & 31) * 64;
  if (bx < 16)
    gemm_core<3>(As, Bs, qb, wqb, bq, Qr, 2048, 2048, m0, bx * 128, CS, SN);
  else if (bx < 20)
    gemm_core<4>(As, Bs, kb, wkb, bk, Kr, 512, 2048, m0, (bx - 16) * 128, CS, SN);
  else
    gemm_core<2>(As, Bs, vb, wvb, bv, Vt, 512, 2048, m0, (bx - 20) * 128, CS, SN);
}

// O projection. 512 blocks, XCD-aware job map.
__global__ __launch_bounds__(256) void gemm_o(
    const bf16_t* __restrict__ Ob, const bf16_t* __restrict__ wob,
    const float* __restrict__ bo, float* __restrict__ out) {
  __shared__ __align__(16) bf16_t As[2 * 64 * 64];
  __shared__ __align__(16) bf16_t Bs[2 * 128 * 64];
  int bid = blockIdx.x;
  int job = (bid & 7) * 64 + (bid >> 3);
  int bx = job >> 5, m0 = (job & 31) * 64;
  gemm_core<0>(As, Bs, Ob, wob, bo, out, 2048, 2048, m0, bx * 128,
               nullptr, nullptr);
}

// ---------------- causal GQA flash attention (R5-verified, ~60 us) ------------
// CLOSED: 7 variants tried (split-KV x2, cross-tile pipeline, reg-V x2,
// mega-fusion, T5 setprio) -- all regressed. This structure is the optimum:
// 512 blocks (32 qt x 16 h), 4 waves x 16 q-rows, K/V double-buffered in LDS
// (64 KB -> 2 blocks/CU), complementary heavy+light pairing, DMA staging with
// source-side XOR swizzle (conflict-free), swapped QK^T, lane-local fixed-max
// exp2 softmax, ds_bpermute crossbar, V in LDS (reg-V spills: R7).
__global__ __launch_bounds__(256, 2) void attn_fwd(
    const bf16_t* __restrict__ Qr, const bf16_t* __restrict__ Kr,
    const bf16_t* __restrict__ Vt, bf16_t* __restrict__ Oo) {
  const int h = blockIdx.y;
  const int bx = blockIdx.x;
  const int qt = (h < 8) ? (31 - bx) : bx;   // complementary co-resident pairing
  const int T = qt + 1;

  const int tid = threadIdx.x;
  const int wv = tid >> 6, lane = tid & 63, quad = lane >> 4, l16 = lane & 15;
  const int q_base = qt * 64 + wv * 16;
  const int hkv = h >> 2;
  const int qg = q_base + l16;               // this lane's q-row (B-operand col)
  const int swzE = (l16 & 7) << 3;           // element-space XOR swizzle (read)

  __shared__ __align__(16) bf16_t Ks[2][64 * 128];   // linear, swizzled content
  __shared__ __align__(16) bf16_t Vs[2][128 * 64];

  short8 qf[4];
  {
    const bf16_t* qp = Qr + (size_t)qg * 2048 + h * 128 + quad * 8;
#pragma unroll
    for (int kc = 0; kc < 4; ++kc) qf[kc] = *(const short8*)(qp + kc * 32);
  }

  const f32x4 zf = {0.f, 0.f, 0.f, 0.f};
  f32x4 o[8];
#pragma unroll
  for (int di = 0; di < 8; ++di) o[di] = zf;
  float l_acc = 0.f;

  auto STAGE = [&](int buf, int t) {
    const int k0 = t * 64;
    bf16_t* KB = &Ks[buf][0];
    bf16_t* VB = &Vs[buf][0];
#pragma unroll
    for (int m = 0; m < 4; ++m) {
      int rK = wv * 16 + m * 4 + (lane >> 4);          // K tile row (k-pos)
      const bf16_t* gK = Kr + (size_t)(k0 + rK) * 512 + hkv * 128
                         + (((lane & 15) ^ ((4 * (m & 1)) | quad)) << 3);
      ld_g2l_16(gK, KB + rK * 128 + ((lane & 15) << 3));
      int rV = wv * 32 + m * 8 + (lane >> 3);          // V tile row (d)
      const bf16_t* gV = Vt + (size_t)(hkv * 128 + rV) * 2048 + k0
                         + (((lane & 7) ^ ((lane >> 3) & 7)) << 3);
      ld_g2l_16(gV, VB + rV * 64 + ((lane & 7) << 3));
    }
  };

  STAGE(0, 0);
  __syncthreads();                // barrier drains vmcnt(0): tile 0 landed
  int buf = 0;

  for (int t = 0; t < T; ++t) {
    if (t + 1 < T) STAGE(buf ^ 1, t + 1);   // prefetch overlaps compute
    const bf16_t* KB = &Ks[buf][0];
    const bf16_t* VB = &Vs[buf][0];
    const int k0 = t * 64;

    // ---- swapped QK^T: sacc[sub][r] = S[k = sub*16+quad*4+r][q = l16] ----
    f32x4 sacc[4];
#pragma unroll
    for (int sub = 0; sub < 4; ++sub) sacc[sub] = zf;
#pragma unroll
    for (int sub = 0; sub < 4; ++sub)
#pragma unroll
      for (int kc = 0; kc < 4; ++kc) {
        short8 kf = *(const short8*)(
            &KB[(sub * 16 + l16) * 128 + ((kc * 32 + quad * 8) ^ swzE)]);
        sacc[sub] = __builtin_amdgcn_mfma_f32_16x16x32_bf16(kf, qf[kc], sacc[sub], 0, 0, 0);
      }

    // ---- lane-local softmax (fixed max, exp2) + pack to bf16 pairs ----
    const bool dg = (k0 + 63 > q_base);
    uint32_t Dw[4][2];
#pragma unroll
    for (int sub = 0; sub < 4; ++sub) {
      float pv[4];
#pragma unroll
      for (int r = 0; r < 4; ++r) {
        float e = exp2f(sacc[sub][r]);
        if (dg) {
          int kg = k0 + sub * 16 + quad * 4 + r;
          if (kg > qg) e = 0.f;
        }
        pv[r] = e;
        l_acc += e;
      }
      asm("v_cvt_pk_bf16_f32 %0, %1, %2" : "=v"(Dw[sub][0]) : "v"(pv[0]), "v"(pv[1]));
      asm("v_cvt_pk_bf16_f32 %0, %1, %2" : "=v"(Dw[sub][1]) : "v"(pv[2]), "v"(pv[3]));
    }

    // ---- C-layout -> A-fragment via ds_bpermute (reg crossbar) ----
    const int aA = ((((quad * 2) & 3) << 4) + l16) << 2;       // d = 0,1
    const int aB = ((((quad * 2 + 1) & 3) << 4) + l16) << 2;   // d = 2,3
    const bool losel = quad < 2;
#define BPERM(a, x) ((uint32_t)__builtin_amdgcn_ds_bpermute((a), (int)(x)))
    union { uint32_t w[4]; short8 v; } U0, U1;
    {
      uint32_t t0, t1;
      t0 = BPERM(aA, Dw[0][0]); t1 = BPERM(aA, Dw[1][0]); U0.w[0] = losel ? t0 : t1;
      t0 = BPERM(aA, Dw[0][1]); t1 = BPERM(aA, Dw[1][1]); U0.w[1] = losel ? t0 : t1;
      t0 = BPERM(aB, Dw[0][0]); t1 = BPERM(aB, Dw[1][0]); U0.w[2] = losel ? t0 : t1;
      t0 = BPERM(aB, Dw[0][1]); t1 = BPERM(aB, Dw[1][1]); U0.w[3] = losel ? t0 : t1;
      t0 = BPERM(aA, Dw[2][0]); t1 = BPERM(aA, Dw[3][0]); U1.w[0] = losel ? t0 : t1;
      t0 = BPERM(aA, Dw[2][1]); t1 = BPERM(aA, Dw[3][1]); U1.w[1] = losel ? t0 : t1;
      t0 = BPERM(aB, Dw[2][0]); t1 = BPERM(aB, Dw[3][0]); U1.w[2] = losel ? t0 : t1;
      t0 = BPERM(aB, Dw[2][1]); t1 = BPERM(aB, Dw[3][1]); U1.w[3] = losel ? t0 : t1;
    }
#undef BPERM
    const short8 pf0 = U0.v, pf1 = U1.v;

    // ---- PV accumulate from V-LDS (swizzled reads) ----
#pragma unroll
    for (int di = 0; di < 8; ++di) {
      short8 vf0 = *(const short8*)(
          &VB[(di * 16 + l16) * 64 + ((quad * 8) ^ swzE)]);
      short8 vf1 = *(const short8*)(
          &VB[(di * 16 + l16) * 64 + ((quad * 8 + 32) ^ swzE)]);
      o[di] = __builtin_amdgcn_mfma_f32_16x16x32_bf16(pf0, vf0, o[di], 0, 0, 0);
      o[di] = __builtin_amdgcn_mfma_f32_16x16x32_bf16(pf1, vf1, o[di], 0, 0, 0);
    }

    __asm__ volatile("s_waitcnt vmcnt(0)" ::: "memory");  // next tile landed
    __syncthreads();   // one barrier/tile: readers done + prefetch visible
    buf ^= 1;
  }

  // epilogue: reduce l across quads, normalize, write bf16
  float lf = l_acc;
  lf += __shfl_xor(lf, 16);
  lf += __shfl_xor(lf, 32);
  float linv[4];
#pragma unroll
  for (int r = 0; r < 4; ++r) linv[r] = 1.0f / __shfl(lf, quad * 4 + r, 64);
#pragma unroll
  for (int di = 0; di < 8; ++di)
#pragma unroll
    for (int r = 0; r < 4; ++r) {
      size_t row = q_base + quad * 4 + r;
      size_t col = h * 128 + di * 16 + l16;
      Oo[row * 2048 + col] = f2bf(o[di][r] * linv[r]);
    }
}

// ---------------- launch ------------------------------------------------------
extern "C" void kernel_launch(void* const* d_in, const int* in_sizes, int n_in,
                              void* d_out, int out_size, void* d_ws, size_t ws_size,
                              hipStream_t stream) {
  (void)in_sizes; (void)n_in; (void)out_size; (void)ws_size;
  const float* query = (const float*)d_in[0];
  const float* key = (const float*)d_in[1];
  const float* value = (const float*)d_in[2];
  const float* Wq = (const float*)d_in[3];
  const float* bq = (const float*)d_in[4];
  const float* Wk = (const float*)d_in[5];
  const float* bk = (const float*)d_in[6];
  const float* Wv = (const float*)d_in[7];
  const float* bv = (const float*)d_in[8];
  const float* Wo = (const float*)d_in[9];
  const float* bo = (const float*)d_in[10];
  float* out = (float*)d_out;

  char* ws = (char*)d_ws;
  const size_t MB = 1024 * 1024;
  bf16_t* qb  = (bf16_t*)(ws + 0 * MB);    // 8 MB
  bf16_t* kb  = (bf16_t*)(ws + 8 * MB);    // 8 MB
  bf16_t* vb  = (bf16_t*)(ws + 16 * MB);   // 8 MB
  bf16_t* wqb = (bf16_t*)(ws + 24 * MB);   // 8 MB
  bf16_t* wkb = (bf16_t*)(ws + 32 * MB);   // 2 MB
  bf16_t* wvb = (bf16_t*)(ws + 34 * MB);   // 2 MB
  bf16_t* wob = (bf16_t*)(ws + 36 * MB);   // 8 MB
  bf16_t* Qr  = (bf16_t*)(ws + 44 * MB);   // 8 MB  roped+scaled Q (x log2e)
  bf16_t* Kr  = (bf16_t*)(ws + 52 * MB);   // 2 MB  roped K
  bf16_t* Vt  = (bf16_t*)(ws + 54 * MB);   // 2 MB  V^T (512 x 2048)
  bf16_t* Ob  = (bf16_t*)(ws + 56 * MB);   // 8 MB  attn out (bf16)
  float*  CS  = (float*)(ws + 64 * MB);    // 512 KB rope cos table
  float*  SN  = (float*)(ws + 64 * MB + 512 * 1024);  // 512 KB rope sin

  convert_all<<<22528, 256, 0, stream>>>(query, key, value, Wq, Wo, Wk, Wv,
                                         qb, kb, vb, wqb, wob, wkb, wvb, CS, SN);
  gemm_qkv<<<768, 256, 0, stream>>>(qb, kb, vb, wqb, wkb, wvb,
                                    bq, bk, bv, Qr, Kr, Vt, CS, SN);
  attn_fwd<<<dim3(32, 16), 256, 0, stream>>>(Qr, Kr, Vt, Ob);
  gemm_o<<<512, 256, 0, stream>>>(Ob, wob, bo, out);
}